// Round 11
// baseline (570.318 us; speedup 1.0000x reference)
//
#include <hip/hip_runtime.h>
#include <cfloat>

#define NROWS 65536
#define DIM   256
#define KCB   4096

#define EPS_WIN  1.8e-4f
#define CAND_CAP 16
#define SROWS    64     // rows per screen block
#define KTW      256    // codebook cols per kt tile

typedef __attribute__((ext_vector_type(8)))  short short8;
typedef __attribute__((ext_vector_type(4)))  float f32x4;
typedef __attribute__((ext_vector_type(16))) float f32x16;

// ---------------- fp32 -> bf16 RNE ----------------
__device__ inline unsigned short f2bf(float x) {
  unsigned int u = __float_as_uint(x);
  return (unsigned short)((u + 0x7fffu + ((u >> 16) & 1u)) >> 16);
}

// ---------------- fused prep: bf16 convert + squared norms, one pass ----------------
__global__ void prep_norms_kernel(const float* __restrict__ z, const float* __restrict__ cb,
                                  unsigned short* __restrict__ zh, unsigned short* __restrict__ eh,
                                  float* __restrict__ znorm, float* __restrict__ enorm) {
  const int r    = blockIdx.x * 4 + (threadIdx.x >> 6);
  const int lane = threadIdx.x & 63;
  const float* src; unsigned short* dst; float* nrm; int row;
  if (r < NROWS) { src = z;  dst = zh; nrm = znorm; row = r; }
  else           { src = cb; dst = eh; nrm = enorm; row = r - NROWS; }
  const float4 v = ((const float4*)(src + (size_t)row * DIM))[lane];
  union { unsigned short us[4]; uint2 u2; } o;
  o.us[0] = f2bf(v.x); o.us[1] = f2bf(v.y); o.us[2] = f2bf(v.z); o.us[3] = f2bf(v.w);
  *(uint2*)(dst + (size_t)row * DIM + lane * 4) = o.u2;
  float s = v.x * v.x + v.y * v.y + v.z * v.z + v.w * v.w;
  #pragma unroll
  for (int off = 32; off > 0; off >>= 1) s += __shfl_down(s, off);
  if (lane == 0) nrm[row] = s;
}

// ---------------- MFMA screen: 32x32x16, 2x2 frags, 256-wide kt tiles ----------------
// Block: 64 rows x 256 cols/kt. 4 waves; wave wv owns cols [wv*64, wv*64+64)
// as 2x2 fragments of 32x32x16 bf16 (acc = 4 x f32x16).
// A resident in LDS 32 KB (dc32-chunked 64B rows, XOR-swizzled, gll-staged).
// B double-buffered 2x16 KB (256 cols x 32 depth per chunk), staged one chunk
// ahead via global_load_lds. 8 chunks/kt, 1 barrier each; per-kt epilogue
// shares per-row tile minima across the 4 col-quarter waves via LDS.
// Screen dist is SHIFTED: s = enorm[k] - 2*dot (argmin/window shift-invariant).
__launch_bounds__(256, 2)
__global__ void screen_kernel(const unsigned short* __restrict__ zh,
                              const unsigned short* __restrict__ eh,
                              const float* __restrict__ enorm,
                              unsigned int* __restrict__ counts,
                              unsigned short* __restrict__ cands) {
  __shared__ __align__(16) unsigned short a_s[8][SROWS][32];   // 32 KB
  __shared__ __align__(16) unsigned short b_s[2][KTW][32];     // 2 x 16 KB
  __shared__ __align__(16) float tilemin_s[4][SROWS];          // 1 KB
  __shared__ unsigned int cnt_s[SROWS];
  __shared__ unsigned short cand_s[SROWS * CAND_CAP];

  const int tid = threadIdx.x;
  const int wv  = tid >> 6;
  const int ln  = tid & 63;
  const int l31 = ln & 31;
  const int hi  = ln >> 5;
  const int rbase = blockIdx.x * SROWS;

  if (tid < SROWS) cnt_s[tid] = 0u;

  unsigned short* bflat = &b_s[0][0][0];

  // ---- stage A (32 KB) + B chunk (kt0,ch0) (16 KB); one drain barrier ----
  {
    const unsigned short* abase = zh + (size_t)rbase * DIM;
    unsigned short* aflat = &a_s[0][0][0];
    #pragma unroll
    for (int i = 0; i < 8; ++i) {
      const int G  = i * 256 + tid;               // 16B granule id
      const int dc = G >> 8, rem = G & 255;
      const int c  = rem >> 2, sw = rem & 3;
      const int s4 = sw ^ ((c >> 1) & 3);
      __builtin_amdgcn_global_load_lds(
          (const uint4*)(abase + (size_t)c * 256 + dc * 32 + s4 * 8),
          (uint4*)(aflat + (size_t)G * 8), 16, 0, 0);
    }
    #pragma unroll
    for (int i = 0; i < 4; ++i) {
      const int G  = i * 256 + tid;               // 0..1023
      const int c  = G >> 2, sw = G & 3;
      const int s4 = sw ^ ((c >> 1) & 3);
      __builtin_amdgcn_global_load_lds(
          (const uint4*)(eh + (size_t)c * 256 + s4 * 8),
          (uint4*)(bflat + (size_t)G * 8), 16, 0, 0);
    }
  }
  __syncthreads();

  // constant per-thread address pieces
  const int axor = (l31 >> 1) & 3;      // == ((row>>1)&3) for rows l31 and 32+l31,
                                        // and ((col>>1)&3) for cols wv*64+fc*32+l31
  float rm[2][16];
  #pragma unroll
  for (int fr = 0; fr < 2; ++fr)
    #pragma unroll
    for (int rg = 0; rg < 16; ++rg) rm[fr][rg] = FLT_MAX;

  int cur = 0;

  #pragma unroll 1
  for (int kt = 0; kt < KCB / KTW; ++kt) {
    const int kcb0 = kt * KTW;

    f32x16 acc[2][2];
    #pragma unroll
    for (int fr = 0; fr < 2; ++fr)
      #pragma unroll
      for (int fc = 0; fc < 2; ++fc)
        #pragma unroll
        for (int rg = 0; rg < 16; ++rg) acc[fr][fc][rg] = 0.0f;

    #pragma unroll 1
    for (int ch = 0; ch < 8; ++ch) {
      // ---- issue NEXT chunk's stage into buf[cur^1] (wraps at end: benign) ----
      {
        const int t   = (kt * 8 + ch + 1) & 127;
        const int nkt = t >> 3, nch = t & 7;
        unsigned short* bn = bflat + (size_t)(cur ^ 1) * (KTW * 32);
        #pragma unroll
        for (int i = 0; i < 4; ++i) {
          const int G  = i * 256 + tid;
          const int c  = G >> 2, sw = G & 3;
          const int s4 = sw ^ ((c >> 1) & 3);
          __builtin_amdgcn_global_load_lds(
              (const uint4*)(eh + (size_t)(nkt * KTW + c) * 256 + nch * 32 + s4 * 8),
              (uint4*)(bn + (size_t)G * 8), 16, 0, 0);
        }
      }

      // ---- compute on buf[cur], depth chunk ch (32 = 2 K-steps of 16) ----
      #pragma unroll
      for (int s = 0; s < 2; ++s) {
        const int sl = (s * 2 + hi) ^ axor;   // 16B slot within 64B row
        short8 af[2], bf[2];
        #pragma unroll
        for (int fr = 0; fr < 2; ++fr)
          af[fr] = *(const short8*)(&a_s[ch][fr * 32 + l31][sl * 8]);
        #pragma unroll
        for (int fc = 0; fc < 2; ++fc)
          bf[fc] = *(const short8*)(&b_s[cur][wv * 64 + fc * 32 + l31][sl * 8]);
        #pragma unroll
        for (int fr = 0; fr < 2; ++fr)
          #pragma unroll
          for (int fc = 0; fc < 2; ++fc)
            acc[fr][fc] = __builtin_amdgcn_mfma_f32_32x32x16_bf16(
                af[fr], bf[fc], acc[fr][fc], 0, 0, 0);
      }

      __syncthreads();   // next stage landed; cur's readers done before overwrite
      cur ^= 1;
    }

    // ---- epilogue: shifted dist, per-row tile-min across all 256 cols ----
    const float en0 = enorm[kcb0 + wv * 64 + l31];        // fc=0 column
    const float en1 = enorm[kcb0 + wv * 64 + 32 + l31];   // fc=1 column

    // per-(fr,reg) min over this wave's 64 cols
    float tm[2][16];
    #pragma unroll
    for (int fr = 0; fr < 2; ++fr)
      #pragma unroll
      for (int rg = 0; rg < 16; ++rg) {
        const float d0 = fmaf(-2.0f, acc[fr][0][rg], en0);
        const float d1 = fmaf(-2.0f, acc[fr][1][rg], en1);
        float v = fminf(d0, d1);
        v = fminf(v, __shfl_xor(v, 1));
        v = fminf(v, __shfl_xor(v, 2));
        v = fminf(v, __shfl_xor(v, 4));
        v = fminf(v, __shfl_xor(v, 8));
        v = fminf(v, __shfl_xor(v, 16));
        tm[fr][rg] = v;    // uniform across the 32 l31-lanes (per hi)
      }

    if (l31 == 0) {
      #pragma unroll
      for (int fr = 0; fr < 2; ++fr)
        #pragma unroll
        for (int rg = 0; rg < 16; ++rg)
          tilemin_s[wv][fr * 32 + (rg & 3) + 8 * (rg >> 2) + 4 * hi] = tm[fr][rg];
    }
    __syncthreads();

    if (tid < SROWS)
      tilemin_s[0][tid] = fminf(fminf(tilemin_s[0][tid], tilemin_s[1][tid]),
                                fminf(tilemin_s[2][tid], tilemin_s[3][tid]));
    __syncthreads();

    // combined per-row minima -> rm update + guard
    float gmin = FLT_MAX;
    #pragma unroll
    for (int fr = 0; fr < 2; ++fr)
      #pragma unroll
      for (int g = 0; g < 4; ++g) {
        const f32x4 cv = *(const f32x4*)(&tilemin_s[0][fr * 32 + g * 8 + 4 * hi]);
        #pragma unroll
        for (int j = 0; j < 4; ++j) {
          const int rg = g * 4 + j;
          const float m = fminf(rm[fr][rg], cv[j]);
          rm[fr][rg] = m;
          gmin = fminf(gmin, tm[fr][rg] - m);
        }
      }

    if (__any(gmin <= EPS_WIN)) {
      #pragma unroll
      for (int fr = 0; fr < 2; ++fr)
        #pragma unroll
        for (int rg = 0; rg < 16; ++rg) {
          const float th = rm[fr][rg] + EPS_WIN;
          const int row = fr * 32 + (rg & 3) + 8 * (rg >> 2) + 4 * hi;
          const float d0 = fmaf(-2.0f, acc[fr][0][rg], en0);
          if (d0 <= th) {
            const unsigned int pos = atomicAdd(&cnt_s[row], 1u);
            if (pos < CAND_CAP)
              cand_s[row * CAND_CAP + pos] =
                  (unsigned short)(kcb0 + wv * 64 + l31);
          }
          const float d1 = fmaf(-2.0f, acc[fr][1][rg], en1);
          if (d1 <= th) {
            const unsigned int pos = atomicAdd(&cnt_s[row], 1u);
            if (pos < CAND_CAP)
              cand_s[row * CAND_CAP + pos] =
                  (unsigned short)(kcb0 + wv * 64 + 32 + l31);
          }
        }
    }
    __syncthreads();   // rm/tilemin consumers done before next kt reuses tilemin_s
  }

  if (tid < SROWS) counts[rbase + tid] = cnt_s[tid];
  for (int i = tid; i < SROWS * CAND_CAP; i += 256)
    cands[(size_t)rbase * CAND_CAP + i] = cand_s[i];
}

// ---------------- exact fp32 rescore + fused output/loss ----------------
__global__ void rescore_kernel(const float* __restrict__ z, const float* __restrict__ cb,
                               const float* __restrict__ znorm, const float* __restrict__ enorm,
                               const unsigned int* __restrict__ counts,
                               const unsigned short* __restrict__ cands,
                               float* __restrict__ out_zq, float* __restrict__ out_idx,
                               float* __restrict__ partials) {
  const int gw  = (blockIdx.x * 256 + threadIdx.x) >> 6;
  const int ln  = threadIdx.x & 63;
  const int row = gw * 4 + (ln >> 4);
  const int ci  = ln & 15;
  const unsigned int cnt = counts[row];
  if (cnt > CAND_CAP) return;   // fallback owns this row

  const int active = ci < (int)cnt;
  const int k = active ? (int)cands[(size_t)row * CAND_CAP + ci] : 0;
  const float4* zr4 = (const float4*)(z  + (size_t)row * DIM);
  const float4* er4 = (const float4*)(cb + (size_t)k   * DIM);
  float ax = 0.f, ay = 0.f, az = 0.f, aw = 0.f;
  #pragma unroll 4
  for (int d = 0; d < DIM / 4; ++d) {
    const float4 zv = zr4[d], ev = er4[d];
    ax = fmaf(zv.x, ev.x, ax); ay = fmaf(zv.y, ev.y, ay);
    az = fmaf(zv.z, ev.z, az); aw = fmaf(zv.w, ev.w, aw);
  }
  const float dot = (ax + ay) + (az + aw);
  const float dist = fmaf(-2.0f, dot, znorm[row] + enorm[k]);
  float bv = active ? dist : FLT_MAX;
  int   bk = active ? k : 0x7fffffff;
  #pragma unroll
  for (int off = 1; off < 16; off <<= 1) {
    const float ov = __shfl_xor(bv, off);
    const int   ok = __shfl_xor(bk, off);
    if (ov < bv || (ov == bv && ok < bk)) { bv = ov; bk = ok; }
  }
  // all 16 lanes agree on bk; fused output
  const float4* br4 = (const float4*)(cb + (size_t)bk * DIM);
  float4* o4 = (float4*)(out_zq + (size_t)row * DIM);
  float sq = 0.0f;
  #pragma unroll
  for (int t = 0; t < 4; ++t) {
    const int p = ci + 16 * t;
    const float4 zv = zr4[p], ev = br4[p];
    float4 st;
    const float dx = ev.x - zv.x, dy = ev.y - zv.y, dz = ev.z - zv.z, dw = ev.w - zv.w;
    st.x = zv.x + dx; st.y = zv.y + dy; st.z = zv.z + dz; st.w = zv.w + dw;
    o4[p] = st;
    sq += dx * dx + dy * dy + dz * dz + dw * dw;
  }
  #pragma unroll
  for (int off = 1; off < 16; off <<= 1) sq += __shfl_xor(sq, off);
  if (ci == 0) { out_idx[row] = (float)bk; partials[row] = sq; }
}

// ---------------- fallback: exact full rescan + fused output for overflow rows ----------------
__global__ void fallback_kernel(const float* __restrict__ z, const float* __restrict__ cb,
                                const float* __restrict__ znorm, const float* __restrict__ enorm,
                                const unsigned int* __restrict__ counts,
                                float* __restrict__ out_zq, float* __restrict__ out_idx,
                                float* __restrict__ partials) {
  __shared__ float bd_s[256];
  __shared__ int   bk_s[256];
  const int tid = threadIdx.x;
  for (int row = blockIdx.x; row < NROWS; row += gridDim.x) {
    if (counts[row] <= CAND_CAP) continue;   // uniform per block
    const float zn = znorm[row];
    const float* zr = z + (size_t)row * DIM;
    float bv = FLT_MAX; int bk = 0x7fffffff;
    for (int k = tid; k < KCB; k += 256) {
      const float* er = cb + (size_t)k * DIM;
      float acc = 0.0f;
      #pragma unroll 8
      for (int d = 0; d < DIM; ++d) acc = fmaf(zr[d], er[d], acc);
      const float dist = fmaf(-2.0f, acc, zn + enorm[k]);
      if (dist < bv || (dist == bv && k < bk)) { bv = dist; bk = k; }
    }
    bd_s[tid] = bv; bk_s[tid] = bk;
    __syncthreads();
    for (int s = 128; s > 0; s >>= 1) {
      if (tid < s) {
        const float ov = bd_s[tid + s]; const int ok = bk_s[tid + s];
        if (ov < bd_s[tid] || (ov == bd_s[tid] && ok < bk_s[tid])) {
          bd_s[tid] = ov; bk_s[tid] = ok;
        }
      }
      __syncthreads();
    }
    const int kb = bk_s[0];
    const float zv = zr[tid];
    const float ev = cb[(size_t)kb * DIM + tid];
    const float dd = ev - zv;
    out_zq[(size_t)row * DIM + tid] = zv + dd;
    if (tid == 0) out_idx[row] = (float)kb;
    __syncthreads();
    bd_s[tid] = dd * dd;
    __syncthreads();
    for (int s = 128; s > 0; s >>= 1) {
      if (tid < s) bd_s[tid] += bd_s[tid + s];
      __syncthreads();
    }
    if (tid == 0) partials[row] = bd_s[0];
    __syncthreads();
  }
}

// ---------------- loss finalize (generic count) ----------------
__global__ void loss_kernel(const float* __restrict__ partials, int n,
                            float* __restrict__ out_loss) {
  float s = 0.0f;
  for (int i = threadIdx.x; i < n; i += 256) s += partials[i];
  #pragma unroll
  for (int off = 32; off > 0; off >>= 1) s += __shfl_down(s, off);
  __shared__ float ps[4];
  if ((threadIdx.x & 63) == 0) ps[threadIdx.x >> 6] = s;
  __syncthreads();
  if (threadIdx.x == 0)
    *out_loss = 0.25f * (((ps[0] + ps[1]) + (ps[2] + ps[3])) *
                         (1.0f / (float)((size_t)NROWS * DIM)));
}

// ---------------- legacy fp32 path (round-3, used if ws too small) ----------------
__global__ void norms_kernel(const float* __restrict__ x, float* __restrict__ out) {
  const int row  = blockIdx.x * 4 + (threadIdx.x >> 6);
  const int lane = threadIdx.x & 63;
  const float4 v = ((const float4*)(x + (size_t)row * DIM))[lane];
  float s = v.x * v.x + v.y * v.y + v.z * v.z + v.w * v.w;
  #pragma unroll
  for (int off = 32; off > 0; off >>= 1) s += __shfl_down(s, off);
  if (lane == 0) out[row] = s;
}

#define BM 128
#define BK 128
#define BD 32
#define LSTR 36
__launch_bounds__(256, 2)
__global__ void argmin_kernel(const float* __restrict__ z,
                              const float* __restrict__ cb,
                              const float* __restrict__ znorm,
                              const float* __restrict__ enorm,
                              int* __restrict__ idx_out) {
  __shared__ float z_s[BM * LSTR];
  __shared__ float e_s[BK * LSTR];
  __shared__ float zn_s[BM];
  const int tid = threadIdx.x;
  const int tx = tid & 15;
  const int ty = tid >> 4;
  const int rbase = blockIdx.x * BM;
  if (tid < BM) zn_s[tid] = znorm[rbase + tid];
  float bestv[8]; int besti[8];
  #pragma unroll
  for (int i = 0; i < 8; ++i) { bestv[i] = FLT_MAX; besti[i] = 0; }
  for (int kc = 0; kc < KCB; kc += BK) {
    float acc[8][8];
    #pragma unroll
    for (int i = 0; i < 8; ++i)
      #pragma unroll
      for (int j = 0; j < 8; ++j) acc[i][j] = 0.0f;
    for (int dc = 0; dc < DIM; dc += BD) {
      __syncthreads();
      #pragma unroll
      for (int p = 0; p < 4; ++p) {
        const int el = p * 256 + tid;
        const int r  = el >> 3;
        const int c4 = (el & 7) * 4;
        *(float4*)(&z_s[r * LSTR + c4]) =
            *(const float4*)(z + (size_t)(rbase + r) * DIM + dc + c4);
        *(float4*)(&e_s[r * LSTR + c4]) =
            *(const float4*)(cb + (size_t)(kc + r) * DIM + dc + c4);
      }
      __syncthreads();
      #pragma unroll 1
      for (int dd = 0; dd < BD; dd += 4) {
        float4 b[8];
        #pragma unroll
        for (int j = 0; j < 8; ++j)
          b[j] = *(const float4*)(&e_s[(tx + 16 * j) * LSTR + dd]);
        #pragma unroll
        for (int i = 0; i < 8; ++i) {
          const float4 a = *(const float4*)(&z_s[(ty + 16 * i) * LSTR + dd]);
          #pragma unroll
          for (int j = 0; j < 8; ++j)
            acc[i][j] += a.x * b[j].x + a.y * b[j].y + a.z * b[j].z + a.w * b[j].w;
        }
      }
    }
    float en[8];
    #pragma unroll
    for (int j = 0; j < 8; ++j) en[j] = enorm[kc + tx + 16 * j];
    #pragma unroll
    for (int i = 0; i < 8; ++i) {
      const float zn = zn_s[ty + 16 * i];
      #pragma unroll
      for (int j = 0; j < 8; ++j) {
        const float t1 = zn + en[j];
        const float dist = t1 - 2.0f * acc[i][j];
        const int k = kc + tx + 16 * j;
        if (dist < bestv[i]) { bestv[i] = dist; besti[i] = k; }
      }
    }
  }
  #pragma unroll
  for (int i = 0; i < 8; ++i) {
    float lv = bestv[i]; int li = besti[i];
    #pragma unroll
    for (int off = 1; off < 16; off <<= 1) {
      const float ov = __shfl_xor(lv, off);
      const int   oi = __shfl_xor(li, off);
      if (ov < lv || (ov == lv && oi < li)) { lv = ov; li = oi; }
    }
    if (tx == 0) idx_out[rbase + ty + 16 * i] = li;
  }
}

__global__ void gather_kernel(const float* __restrict__ z,
                              const float* __restrict__ cb,
                              const int* __restrict__ idx,
                              float* __restrict__ out_zq,
                              float* __restrict__ out_idx,
                              float* __restrict__ partials) {
  const int row  = blockIdx.x * 4 + (threadIdx.x >> 6);
  const int lane = threadIdx.x & 63;
  const int k = idx[row];
  const float4 zv = ((const float4*)(z  + (size_t)row * DIM))[lane];
  const float4 ev = ((const float4*)(cb + (size_t)k   * DIM))[lane];
  float4 d, st;
  d.x = ev.x - zv.x; d.y = ev.y - zv.y; d.z = ev.z - zv.z; d.w = ev.w - zv.w;
  st.x = zv.x + d.x; st.y = zv.y + d.y; st.z = zv.z + d.z; st.w = zv.w + d.w;
  ((float4*)(out_zq + (size_t)row * DIM))[lane] = st;
  if (lane == 0) out_idx[row] = (float)k;
  float s = d.x * d.x + d.y * d.y + d.z * d.z + d.w * d.w;
  #pragma unroll
  for (int off = 32; off > 0; off >>= 1) s += __shfl_down(s, off);
  __shared__ float ps[4];
  if (lane == 0) ps[threadIdx.x >> 6] = s;
  __syncthreads();
  if (threadIdx.x == 0)
    partials[blockIdx.x] = (ps[0] + ps[1]) + (ps[2] + ps[3]);
}

extern "C" void kernel_launch(void* const* d_in, const int* in_sizes, int n_in,
                              void* d_out, int out_size, void* d_ws, size_t ws_size,
                              hipStream_t stream) {
  const float* z  = (const float*)d_in[0];   // [65536, 256]
  const float* cb = (const float*)d_in[1];   // [4096, 256]

  float* out_zq   = (float*)d_out;
  float* out_idx  = out_zq + (size_t)NROWS * DIM;
  float* out_loss = out_idx + NROWS;

  // fast-path workspace layout (bytes)
  char* w = (char*)d_ws;
  unsigned short* zh    = (unsigned short*)(w);                   // 33554432
  unsigned short* eh    = (unsigned short*)(w + 33554432);        //  2097152
  float* enorm          = (float*)(w + 35651584);                 //    16384
  float* znorm          = (float*)(w + 35667968);                 //   262144
  unsigned int* counts  = (unsigned int*)(w + 36192256);          //   262144
  unsigned short* cands = (unsigned short*)(w + 36454400);        //  2097152
  float* partials       = (float*)(w + 38551552);                 //   262144
  const size_t NEED = 38813696;

  if (ws_size >= NEED) {
    hipLaunchKernelGGL(prep_norms_kernel, dim3((NROWS + KCB) / 4), dim3(256), 0, stream,
                       z, cb, zh, eh, znorm, enorm);
    hipLaunchKernelGGL(screen_kernel, dim3(NROWS / SROWS), dim3(256), 0, stream,
                       zh, eh, enorm, counts, cands);
    hipLaunchKernelGGL(rescore_kernel, dim3(NROWS / 16), dim3(256), 0, stream,
                       z, cb, znorm, enorm, counts, cands, out_zq, out_idx, partials);
    hipLaunchKernelGGL(fallback_kernel, dim3(256), dim3(256), 0, stream,
                       z, cb, znorm, enorm, counts, out_zq, out_idx, partials);
    hipLaunchKernelGGL(loss_kernel, dim3(1), dim3(256), 0, stream,
                       partials, NROWS, out_loss);
  } else {
    // legacy (round-3) layout + path
    float* ws         = (float*)d_ws;
    float* enorm_l    = ws;
    float* znorm_l    = ws + KCB;
    int*   idx_l      = (int*)(ws + KCB + NROWS);
    float* partials_l = ws + KCB + 2 * NROWS;
    hipLaunchKernelGGL(norms_kernel, dim3(KCB / 4), dim3(256), 0, stream, cb, enorm_l);
    hipLaunchKernelGGL(norms_kernel, dim3(NROWS / 4), dim3(256), 0, stream, z, znorm_l);
    hipLaunchKernelGGL(argmin_kernel, dim3(NROWS / BM), dim3(256), 0, stream,
                       z, cb, znorm_l, enorm_l, idx_l);
    hipLaunchKernelGGL(gather_kernel, dim3(NROWS / 4), dim3(256), 0, stream,
                       z, cb, idx_l, out_zq, out_idx, partials_l);
    hipLaunchKernelGGL(loss_kernel, dim3(1), dim3(256), 0, stream,
                       partials_l, NROWS / 4, out_loss);
  }
}